// Round 8
// baseline (272.288 us; speedup 1.0000x reference)
//
#include <hip/hip_runtime.h>
#include <hip/hip_bf16.h>
#include <cstdint>

using bf16 = __hip_bfloat16;
typedef __attribute__((ext_vector_type(8))) short short8;
typedef __attribute__((ext_vector_type(4))) float floatx4;

// Problem constants
static constexpr int BATCH = 8192;
static constexpr int K1    = 2304;   // OBS + NH
static constexpr int N1    = 2048;   // NH
static constexpr int K2    = 2048;   // NH
static constexpr int N2    = 256;    // 2*LAT
static constexpr int KT1   = K1 / 64;  // 36 K-tiles of 64

__device__ __forceinline__ void gload_lds16(const void* g, void* l) {
  __builtin_amdgcn_global_load_lds(
      (const __attribute__((address_space(1))) void*)g,
      (__attribute__((address_space(3))) void*)l, 16, 0, 0);
}

// tanh(x) = 1 - 2/(1+e^{2x}); exp2-based, saturates to +/-1, err ~1e-6
__device__ __forceinline__ float fast_tanh(float x) {
  float e = __builtin_amdgcn_exp2f(x * 2.8853900817779268f);  // 2*log2(e)
  return 1.0f - 2.0f * __builtin_amdgcn_rcpf(e + 1.0f);
}

__device__ __forceinline__ short8 cvt8(const float* src) {
  float4 a = ((const float4*)src)[0];
  float4 b = ((const float4*)src)[1];
  union { short8 v; bf16 e[8]; } u;
  u.e[0] = __float2bfloat16(a.x); u.e[1] = __float2bfloat16(a.y);
  u.e[2] = __float2bfloat16(a.z); u.e[3] = __float2bfloat16(a.w);
  u.e[4] = __float2bfloat16(b.x); u.e[5] = __float2bfloat16(b.y);
  u.e[6] = __float2bfloat16(b.z); u.e[7] = __float2bfloat16(b.w);
  return u.v;
}

// ------- fused prep: cat(x,h)->bf16, W_i2h->bf16, W_h2o->bf16, bias seed ---
static constexpr int SEG0 = BATCH * (K1 / 8);          // 2,359,296
static constexpr int SEG1 = N1 * K1 / 8;               //   589,824
static constexpr int SEG2 = N2 * K2 / 8;               //    65,536
static constexpr int SEG3 = BATCH * (N2 / 4);          //   524,288 (bias seed)
__global__ __launch_bounds__(256) void prep(
    const float* __restrict__ x, const float* __restrict__ h,
    const float* __restrict__ W1, const float* __restrict__ W2,
    const float* __restrict__ b2,
    bf16* __restrict__ comb, bf16* __restrict__ W1b, bf16* __restrict__ W2b,
    float* __restrict__ outp) {
  int i = blockIdx.x * 256 + threadIdx.x;
  if (i < SEG0) {
    int row  = i / 288;
    int slot = i - row * 288;
    const float* src = (slot < 32) ? (x + (size_t)row * 256 + slot * 8)
                                   : (h + (size_t)row * 2048 + (slot - 32) * 8);
    *(short8*)(comb + (size_t)row * 2304 + slot * 8) = cvt8(src);
  } else if (i < SEG0 + SEG1) {
    int j = i - SEG0;
    *(short8*)(W1b + (size_t)j * 8) = cvt8(W1 + (size_t)j * 8);
  } else if (i < SEG0 + SEG1 + SEG2) {
    int j = i - (SEG0 + SEG1);
    *(short8*)(W2b + (size_t)j * 8) = cvt8(W2 + (size_t)j * 8);
  } else {
    int j = i - (SEG0 + SEG1 + SEG2);   // out = bias broadcast (atomic seed)
    float4 b = ((const float4*)b2)[j & 63];
    ((float4*)outp)[j] = b;
  }
}

// ---------------- GEMM1: h_new = tanh(A @ W^T + bias); FUSED GEMM2 --------
// K-loop identical to R5 (pipelined reads, 1 barrier/phase, counted vmcnt).
// Fused epilogue v2: after tanh -> store hf32 + write bf16 h-tile to LDS
// (staging buffer reused; swizzle (col>>3)^(row&7)), then mini-GEMM
// 256x256x256 vs the L2-resident W2 k-slice with DOUBLE-BUFFERED B-register
// prefetch (R7 issued the 4 B-loads inside each of 8 ks steps serially ->
// ~8 exposed L2 latencies; R8 prefetches ks+1 before ks's 32 MFMA).
// Emission: f32 atomics into bias-seeded out (removes R7's 67 MB `part`
// write burst and the reduce8 pass; out is 8.4 MB -> L2-resident, 8 adds
// per address spread over the epilogue window).
__global__ __launch_bounds__(512, 2) void gemm1_tanh(
    const bf16* __restrict__ A, const bf16* __restrict__ W,
    const float* __restrict__ bias, const bf16* __restrict__ W2b,
    float* __restrict__ hf32, float* __restrict__ outp) {
  __shared__ __align__(16) char ldsb_s[131072];  // staging [2][2][2][16KB] / htile
  char* const ldsb = ldsb_s;
  const int t    = threadIdx.x;         // 0..511
  const int lane = t & 63;
  const int wave = t >> 6;              // 0..7
  const int wm   = (wave >> 2) * 128;   // 0 or 128
  const int wn   = (wave & 3) * 64;     // 0,64,128,192
  const int quad = lane >> 4;
  const int r15  = lane & 15;

  // LDS read bases (byte offsets within one [kh] bank of 16384 B)
  const int swz   = ((quad ^ ((r15 >> 1) & 3)) << 4);
  const int baseA = wm * 64 + r15 * 64 + swz;            // + mtg*4096 + mt*1024
  const int baseB = 32768 + wn * 64 + r15 * 64 + swz;    // + nt*1024

  // staging: thread covers row r = half*128 + (t>>2), 16B slot s = t&3,
  // pre-swizzled global col so LDS dest stays linear (dest = half*8192 + t*16)
  const int srow  = t >> 2;             // 0..127
  const int sslot = t & 3;
  const int sq    = (sslot ^ ((srow >> 1) & 3)) * 8;  // elem offset in K-half

  const size_t Abase = (size_t)blockIdx.x * 256 * K1;
  const size_t Bbase = (size_t)blockIdx.y * 256 * K1;
  const size_t gA0 = Abase + (size_t)srow * K1 + sq;
  const size_t gA1 = Abase + (size_t)(srow + 128) * K1 + sq;
  const size_t gB0 = Bbase + (size_t)srow * K1 + sq;
  const size_t gB1 = Bbase + (size_t)(srow + 128) * K1 + sq;
  const int d0 = t * 16, d1 = 8192 + t * 16;   // LDS byte offsets

  // stage one (buf, mat, kh) region from K-tile skt (clamped): 2 gloads
#define STG(sb, mat_, skh, skt) do {                                         \
    const int ktc_ = ((skt) < KT1 ? (skt) : (KT1 - 1));                      \
    const size_t ko_ = (size_t)ktc_ * 64 + (skh) * 32;                       \
    char* const la_ = ldsb + ((sb) << 16) + ((mat_) * 32768) + ((skh) << 14);\
    const bf16* g0_ = (mat_) ? (W + gB0 + ko_) : (A + gA0 + ko_);            \
    const bf16* g1_ = (mat_) ? (W + gB1 + ko_) : (A + gA1 + ko_);            \
    gload_lds16(g0_, la_ + d0);                                              \
    gload_lds16(g1_, la_ + d1);                                              \
  } while (0)

  floatx4 acc[8][4];
  const floatx4 z = {0.f, 0.f, 0.f, 0.f};
#pragma unroll
  for (int i = 0; i < 8; i++)
#pragma unroll
    for (int j = 0; j < 4; j++) acc[i][j] = z;

  short8 afA[4], afB[4], bfA[4], bfB[4];   // double-buffered fragment sets

  // prologue: buf0 kh0+kh1 <- tile 0 (A+B), buf1 kh0 <- tile 1 (A+B)
  STG(0, 0, 0, 0); STG(0, 1, 0, 0);
  STG(0, 0, 1, 0); STG(0, 1, 1, 0);
  STG(1, 0, 0, 1); STG(1, 1, 0, 1);
  asm volatile("s_waitcnt vmcnt(8)" ::: "memory");   // buf0.kh0 landed
  __builtin_amdgcn_s_barrier();
  __builtin_amdgcn_sched_barrier(0);
  {  // pre-issue reads for ph0: (buf0, ks0, mtg0) -> afA, bfA
#pragma unroll
    for (int mt = 0; mt < 4; ++mt)
      afA[mt] = *(const short8*)(ldsb + baseA + mt * 1024);
#pragma unroll
    for (int nt = 0; nt < 4; ++nt)
      bfA[nt] = *(const short8*)(ldsb + baseB + nt * 1024);
  }

  // PH: consume (ccb,cks,cmtg) from AFC/BFC; issue reads (rcb,rks,rmtg) into
  // AFN (and BFN if RB); stage (sb,smat,skh,skt); VMW: vmcnt(6); lgkm(LGS).
#define PH(ccb, cks, cmtg, AFC, BFC, rcb, rks, rmtg, AFN, BFN, RB,           \
           sb, smat, skh, skt, VMW, LGS) do {                                \
    const char* Lr_ = ldsb + ((rcb) << 16) + ((rks) << 14);                  \
    _Pragma("unroll")                                                        \
    for (int mt = 0; mt < 4; ++mt)                                           \
      AFN[mt] = *(const short8*)(Lr_ + baseA + (rmtg) * 4096 + mt * 1024);   \
    if (RB) {                                                                \
      _Pragma("unroll")                                                      \
      for (int nt = 0; nt < 4; ++nt)                                         \
        BFN[nt] = *(const short8*)(Lr_ + baseB + nt * 1024);                 \
    }                                                                        \
    STG(sb, smat, skh, skt);                                                 \
    __builtin_amdgcn_sched_barrier(0);                                       \
    if (VMW) asm volatile("s_waitcnt vmcnt(6)" ::: "memory");                \
    asm volatile("s_waitcnt lgkmcnt(" LGS ")" ::: "memory");                 \
    __builtin_amdgcn_sched_barrier(0);                                       \
    __builtin_amdgcn_s_setprio(1);                                           \
    _Pragma("unroll")                                                        \
    for (int mt = 0; mt < 4; ++mt)                                           \
      _Pragma("unroll")                                                      \
      for (int nt = 0; nt < 4; ++nt)                                         \
        acc[(cmtg) * 4 + mt][nt] = __builtin_amdgcn_mfma_f32_16x16x32_bf16(  \
            AFC[mt], BFC[nt], acc[(cmtg) * 4 + mt][nt], 0, 0, 0);            \
    __builtin_amdgcn_s_setprio(0);                                           \
    __builtin_amdgcn_s_barrier();                                            \
    __builtin_amdgcn_sched_barrier(0);                                       \
  } while (0)

#pragma clang loop unroll(disable)
  for (int t2 = 0; t2 < KT1 / 2; ++t2) {
    const int n = 2 * t2;
    PH(0, 0, 0, afA, bfA,  0, 0, 1, afB, bfB, 0,  1, 0, 1, n + 1, 1, "4");
    PH(0, 0, 1, afB, bfA,  0, 1, 0, afA, bfB, 1,  1, 1, 1, n + 1, 0, "8");
    PH(0, 1, 0, afA, bfB,  0, 1, 1, afB, bfA, 0,  0, 0, 0, n + 2, 1, "4");
    PH(0, 1, 1, afB, bfB,  1, 0, 0, afA, bfA, 1,  0, 1, 0, n + 2, 0, "8");
    PH(1, 0, 0, afA, bfA,  1, 0, 1, afB, bfB, 0,  0, 0, 1, n + 2, 1, "4");
    PH(1, 0, 1, afB, bfA,  1, 1, 0, afA, bfB, 1,  0, 1, 1, n + 2, 0, "8");
    PH(1, 1, 0, afA, bfB,  1, 1, 1, afB, bfA, 0,  1, 0, 0, n + 3, 1, "4");
    PH(1, 1, 1, afB, bfB,  0, 0, 0, afA, bfA, 1,  1, 1, 0, n + 3, 0, "8");
  }
#undef PH
#undef STG

  // ======================= fused epilogue (v2) =========================
  // Drain all outstanding staging (tail prefetches) + frag reads, then the
  // staging LDS is dead and can be reused as the 256x256 bf16 h-tile.
  asm volatile("s_waitcnt vmcnt(0) lgkmcnt(0)" ::: "memory");
  __builtin_amdgcn_s_barrier();
  __builtin_amdgcn_sched_barrier(0);

  const int gcol0 = blockIdx.y * 256 + wn;
  float bv[4];
#pragma unroll
  for (int nt = 0; nt < 4; ++nt) bv[nt] = bias[gcol0 + nt * 16 + r15];
  const size_t grow0 = (size_t)blockIdx.x * 256 + wm;

  // htile byte addr: row*512 + swizzled 16B slot + in-slot offset
#define HB(row, col) ((row) * 512 + (((((col) >> 3) ^ ((row) & 7))) << 4) + \
                      (((col) & 7) << 1))
#pragma unroll
  for (int mt = 0; mt < 8; ++mt) {
#pragma unroll
    for (int i = 0; i < 4; ++i) {
      const int lrow = wm + mt * 16 + quad * 4 + i;
      const size_t rb = (grow0 + mt * 16 + quad * 4 + i) * (size_t)N1;
#pragma unroll
      for (int nt = 0; nt < 4; ++nt) {
        const int lcol = wn + nt * 16 + r15;
        float v = fast_tanh(acc[mt][nt][i] + bv[nt]);
        hf32[rb + gcol0 - wn + lcol] = v;   // = rb + blockIdx.y*256 + lcol
        *(bf16*)(ldsb + HB(lrow, lcol)) = __float2bfloat16(v);
      }
    }
  }
  asm volatile("s_waitcnt lgkmcnt(0)" ::: "memory");
  __builtin_amdgcn_s_barrier();
  __builtin_amdgcn_sched_barrier(0);

  // mini-GEMM: out2[256r x 256n2] += htile[256r x 256k] @ W2slice^T
  // wave owns 128r x 64n2 (same wm/wn); k = 256 (8 slices of 32).
  // B (global, L2) double-buffered: prefetch ks+1 before ks's MFMA cluster.
#pragma unroll
  for (int i = 0; i < 8; i++)
#pragma unroll
    for (int j = 0; j < 4; j++) acc[i][j] = z;

  const bf16* w2base = W2b + (size_t)blockIdx.y * 256;  // k-slice of W2b[n2][2048]

#define MG_LOADB(BQ, ksn) do {                                               \
    _Pragma("unroll")                                                        \
    for (int nt = 0; nt < 4; ++nt)                                           \
      BQ[nt] = *(const short8*)(w2base +                                     \
                (size_t)(wn + nt * 16 + r15) * 2048 + (ksn) * 32 + quad * 8);\
  } while (0)
#define MG_STEP(BQ, ksc) do {                                                \
    short8 aq_[8];                                                           \
    _Pragma("unroll")                                                        \
    for (int mt = 0; mt < 8; ++mt) {                                         \
      const int row_ = wm + mt * 16 + r15;                                   \
      aq_[mt] = *(const short8*)(ldsb + row_ * 512 +                         \
                                 ((((ksc) * 4 + quad) ^ (row_ & 7))) * 16);  \
    }                                                                        \
    _Pragma("unroll")                                                        \
    for (int mt = 0; mt < 8; ++mt)                                           \
      _Pragma("unroll")                                                      \
      for (int nt = 0; nt < 4; ++nt)                                         \
        acc[mt][nt] = __builtin_amdgcn_mfma_f32_16x16x32_bf16(               \
            aq_[mt], BQ[nt], acc[mt][nt], 0, 0, 0);                          \
  } while (0)

  {
    short8 bqA[4], bqB[4];
    MG_LOADB(bqA, 0);
    MG_LOADB(bqB, 1); MG_STEP(bqA, 0);
    MG_LOADB(bqA, 2); MG_STEP(bqB, 1);
    MG_LOADB(bqB, 3); MG_STEP(bqA, 2);
    MG_LOADB(bqA, 4); MG_STEP(bqB, 3);
    MG_LOADB(bqB, 5); MG_STEP(bqA, 4);
    MG_LOADB(bqA, 6); MG_STEP(bqB, 5);
    MG_LOADB(bqB, 7); MG_STEP(bqA, 6);
    MG_STEP(bqB, 7);
  }
#undef MG_LOADB
#undef MG_STEP
#undef HB

  // emit: f32 atomics into bias-seeded out (L2-resident, 8 adds/address)
#pragma unroll
  for (int mt = 0; mt < 8; ++mt) {
#pragma unroll
    for (int i = 0; i < 4; ++i) {
      const size_t gr = grow0 + mt * 16 + quad * 4 + i;
#pragma unroll
      for (int nt = 0; nt < 4; ++nt) {
        const int gc = wn + nt * 16 + r15;
        unsafeAtomicAdd(&outp[gr * N2 + gc], acc[mt][nt][i]);
      }
    }
  }
}

extern "C" void kernel_launch(void* const* d_in, const int* in_sizes, int n_in,
                              void* d_out, int out_size, void* d_ws,
                              size_t ws_size, hipStream_t stream) {
  const float* x     = (const float*)d_in[0];  // [8192, 256]
  const float* h     = (const float*)d_in[1];  // [8192, 2048]
  const float* W_i2h = (const float*)d_in[2];  // [2048, 2304]
  const float* b_i2h = (const float*)d_in[3];  // [2048]
  const float* W_h2o = (const float*)d_in[4];  // [256, 2048]
  const float* b_h2o = (const float*)d_in[5];  // [256]

  float* out       = (float*)d_out;                    // [8192, 256]
  float* hnew_f32  = out + (size_t)BATCH * N2;         // [8192, 2048]

  bf16* comb   = (bf16*)d_ws;                          // 8192*2304  (37.75 MB)
  bf16* Wi2h_b = comb + (size_t)BATCH * K1;            // 2048*2304  ( 9.44 MB)
  bf16* Wh2o_b = Wi2h_b + (size_t)N1 * K1;             // 256*2048   ( 1.00 MB)

  // fused converters + bias seed (atomic accumulation target)
  prep<<<(SEG0 + SEG1 + SEG2 + SEG3) / 256, 256, 0, stream>>>(
      x, h, W_i2h, W_h2o, b_h2o, comb, Wi2h_b, Wh2o_b, out);

  // GEMM1 + fused GEMM2 (atomic emit); grid 32 x 8 = 256 blocks (1 per CU)
  gemm1_tanh<<<dim3(BATCH / 256, N1 / 256), 512, 0, stream>>>(
      comb, Wi2h_b, b_i2h, Wh2o_b, hnew_f32, out);
}

// Round 9
// 247.591 us; speedup vs baseline: 1.0997x; 1.0997x over previous
//
#include <hip/hip_runtime.h>
#include <hip/hip_bf16.h>
#include <cstdint>

using bf16 = __hip_bfloat16;
typedef __attribute__((ext_vector_type(8))) short short8;
typedef __attribute__((ext_vector_type(4))) float floatx4;

// Problem constants
static constexpr int BATCH = 8192;
static constexpr int K1    = 2304;   // OBS + NH
static constexpr int N1    = 2048;   // NH
static constexpr int K2    = 2048;   // NH
static constexpr int N2    = 256;    // 2*LAT
static constexpr int KT1   = K1 / 64;  // 36 K-tiles of 64

__device__ __forceinline__ void gload_lds16(const void* g, void* l) {
  __builtin_amdgcn_global_load_lds(
      (const __attribute__((address_space(1))) void*)g,
      (__attribute__((address_space(3))) void*)l, 16, 0, 0);
}

// tanh(x) = 1 - 2/(1+e^{2x}); exp2-based, saturates to +/-1, err ~1e-6
__device__ __forceinline__ float fast_tanh(float x) {
  float e = __builtin_amdgcn_exp2f(x * 2.8853900817779268f);  // 2*log2(e)
  return 1.0f - 2.0f * __builtin_amdgcn_rcpf(e + 1.0f);
}

__device__ __forceinline__ short8 cvt8(const float* src) {
  float4 a = ((const float4*)src)[0];
  float4 b = ((const float4*)src)[1];
  union { short8 v; bf16 e[8]; } u;
  u.e[0] = __float2bfloat16(a.x); u.e[1] = __float2bfloat16(a.y);
  u.e[2] = __float2bfloat16(a.z); u.e[3] = __float2bfloat16(a.w);
  u.e[4] = __float2bfloat16(b.x); u.e[5] = __float2bfloat16(b.y);
  u.e[6] = __float2bfloat16(b.z); u.e[7] = __float2bfloat16(b.w);
  return u.v;
}

// ------- fused prep: cat(x,h)->bf16, W_i2h->bf16, W_h2o->bf16 --------------
// (bias seed only written when outp != nullptr, i.e. atomic-fallback path)
static constexpr int SEG0 = BATCH * (K1 / 8);          // 2,359,296
static constexpr int SEG1 = N1 * K1 / 8;               //   589,824
static constexpr int SEG2 = N2 * K2 / 8;               //    65,536
static constexpr int SEG3 = BATCH * (N2 / 4);          //   524,288 (bias seed)
__global__ __launch_bounds__(256) void prep(
    const float* __restrict__ x, const float* __restrict__ h,
    const float* __restrict__ W1, const float* __restrict__ W2,
    const float* __restrict__ b2,
    bf16* __restrict__ comb, bf16* __restrict__ W1b, bf16* __restrict__ W2b,
    float* __restrict__ outp) {
  int i = blockIdx.x * 256 + threadIdx.x;
  if (i < SEG0) {
    int row  = i / 288;
    int slot = i - row * 288;
    const float* src = (slot < 32) ? (x + (size_t)row * 256 + slot * 8)
                                   : (h + (size_t)row * 2048 + (slot - 32) * 8);
    *(short8*)(comb + (size_t)row * 2304 + slot * 8) = cvt8(src);
  } else if (i < SEG0 + SEG1) {
    int j = i - SEG0;
    *(short8*)(W1b + (size_t)j * 8) = cvt8(W1 + (size_t)j * 8);
  } else if (i < SEG0 + SEG1 + SEG2) {
    int j = i - (SEG0 + SEG1);
    *(short8*)(W2b + (size_t)j * 8) = cvt8(W2 + (size_t)j * 8);
  } else if (outp) {
    int j = i - (SEG0 + SEG1 + SEG2);   // out = bias broadcast (atomic seed)
    float4 b = ((const float4*)b2)[j & 63];
    ((float4*)outp)[j] = b;
  }
}

// ---- reduce8: out = bias + sum_{by} part_bf16[by]  (partial-sum path) -----
__global__ __launch_bounds__(256) void reduce8(
    const bf16* __restrict__ part, const float* __restrict__ bias,
    float* __restrict__ out) {
  int i = blockIdx.x * 256 + threadIdx.x;   // 8-float group over [8192*256/8]
  const int col = (i & 31) * 8;
  float4 b0 = *(const float4*)(bias + col);
  float4 b1 = *(const float4*)(bias + col + 4);
  float s[8] = {b0.x, b0.y, b0.z, b0.w, b1.x, b1.y, b1.z, b1.w};
#pragma unroll
  for (int b = 0; b < 8; ++b) {
    short8 p = ((const short8*)(part + (size_t)b * BATCH * N2))[i];
#pragma unroll
    for (int j = 0; j < 8; ++j) {
      union { float f; uint32_t u; } c;
      c.u = ((uint32_t)(uint16_t)p[j]) << 16;
      s[j] += c.f;
    }
  }
  float4 o0 = {s[0], s[1], s[2], s[3]};
  float4 o1 = {s[4], s[5], s[6], s[7]};
  ((float4*)(out + (size_t)i * 8))[0] = o0;
  ((float4*)(out + (size_t)i * 8 + 4))[0] = o1;
}

// ---------------- GEMM1: h_new = tanh(A @ W^T + bias); FUSED GEMM2 --------
// K-loop identical to R5 (pipelined reads, 1 barrier/phase, counted vmcnt).
// Fused epilogue v3: tanh -> hf32 store + bf16 h-tile to LDS (swizzled);
// mini-GEMM 256x256x256 vs L2-resident W2 k-slice with double-buffered
// B-register prefetch (first two quads hoisted above the htile barrier so
// the first L2 latency hides under the LDS write+barrier).
// Emission: MODE 1 = bf16 partial stores to part[by] (reduce8 sums+bias).
//           MODE 0 = f32 atomics into bias-seeded out (ws-too-small path).
// R8 lesson: device-scope f32 atomics (non-coherent per-XCD L2s -> every
// atomic is a memory-side round-trip, 8 writers on the same 8.4 MB window)
// lost ~10 us vs plain partial stores. Partials + reduce is the right shape.
template <int MODE>
__global__ __launch_bounds__(512, 2) void gemm1_tanh(
    const bf16* __restrict__ A, const bf16* __restrict__ W,
    const float* __restrict__ bias, const bf16* __restrict__ W2b,
    float* __restrict__ hf32, float* __restrict__ outp,
    bf16* __restrict__ partp) {
  __shared__ __align__(16) char ldsb_s[131072];  // staging [2][2][2][16KB] / htile
  char* const ldsb = ldsb_s;
  const int t    = threadIdx.x;         // 0..511
  const int lane = t & 63;
  const int wave = t >> 6;              // 0..7
  const int wm   = (wave >> 2) * 128;   // 0 or 128
  const int wn   = (wave & 3) * 64;     // 0,64,128,192
  const int quad = lane >> 4;
  const int r15  = lane & 15;

  // LDS read bases (byte offsets within one [kh] bank of 16384 B)
  const int swz   = ((quad ^ ((r15 >> 1) & 3)) << 4);
  const int baseA = wm * 64 + r15 * 64 + swz;            // + mtg*4096 + mt*1024
  const int baseB = 32768 + wn * 64 + r15 * 64 + swz;    // + nt*1024

  // staging: thread covers row r = half*128 + (t>>2), 16B slot s = t&3,
  // pre-swizzled global col so LDS dest stays linear (dest = half*8192 + t*16)
  const int srow  = t >> 2;             // 0..127
  const int sslot = t & 3;
  const int sq    = (sslot ^ ((srow >> 1) & 3)) * 8;  // elem offset in K-half

  const size_t Abase = (size_t)blockIdx.x * 256 * K1;
  const size_t Bbase = (size_t)blockIdx.y * 256 * K1;
  const size_t gA0 = Abase + (size_t)srow * K1 + sq;
  const size_t gA1 = Abase + (size_t)(srow + 128) * K1 + sq;
  const size_t gB0 = Bbase + (size_t)srow * K1 + sq;
  const size_t gB1 = Bbase + (size_t)(srow + 128) * K1 + sq;
  const int d0 = t * 16, d1 = 8192 + t * 16;   // LDS byte offsets

  // stage one (buf, mat, kh) region from K-tile skt (clamped): 2 gloads
#define STG(sb, mat_, skh, skt) do {                                         \
    const int ktc_ = ((skt) < KT1 ? (skt) : (KT1 - 1));                      \
    const size_t ko_ = (size_t)ktc_ * 64 + (skh) * 32;                       \
    char* const la_ = ldsb + ((sb) << 16) + ((mat_) * 32768) + ((skh) << 14);\
    const bf16* g0_ = (mat_) ? (W + gB0 + ko_) : (A + gA0 + ko_);            \
    const bf16* g1_ = (mat_) ? (W + gB1 + ko_) : (A + gA1 + ko_);            \
    gload_lds16(g0_, la_ + d0);                                              \
    gload_lds16(g1_, la_ + d1);                                              \
  } while (0)

  floatx4 acc[8][4];
  const floatx4 z = {0.f, 0.f, 0.f, 0.f};
#pragma unroll
  for (int i = 0; i < 8; i++)
#pragma unroll
    for (int j = 0; j < 4; j++) acc[i][j] = z;

  short8 afA[4], afB[4], bfA[4], bfB[4];   // double-buffered fragment sets

  // prologue: buf0 kh0+kh1 <- tile 0 (A+B), buf1 kh0 <- tile 1 (A+B)
  STG(0, 0, 0, 0); STG(0, 1, 0, 0);
  STG(0, 0, 1, 0); STG(0, 1, 1, 0);
  STG(1, 0, 0, 1); STG(1, 1, 0, 1);
  asm volatile("s_waitcnt vmcnt(8)" ::: "memory");   // buf0.kh0 landed
  __builtin_amdgcn_s_barrier();
  __builtin_amdgcn_sched_barrier(0);
  {  // pre-issue reads for ph0: (buf0, ks0, mtg0) -> afA, bfA
#pragma unroll
    for (int mt = 0; mt < 4; ++mt)
      afA[mt] = *(const short8*)(ldsb + baseA + mt * 1024);
#pragma unroll
    for (int nt = 0; nt < 4; ++nt)
      bfA[nt] = *(const short8*)(ldsb + baseB + nt * 1024);
  }

  // PH: consume (ccb,cks,cmtg) from AFC/BFC; issue reads (rcb,rks,rmtg) into
  // AFN (and BFN if RB); stage (sb,smat,skh,skt); VMW: vmcnt(6); lgkm(LGS).
#define PH(ccb, cks, cmtg, AFC, BFC, rcb, rks, rmtg, AFN, BFN, RB,           \
           sb, smat, skh, skt, VMW, LGS) do {                                \
    const char* Lr_ = ldsb + ((rcb) << 16) + ((rks) << 14);                  \
    _Pragma("unroll")                                                        \
    for (int mt = 0; mt < 4; ++mt)                                           \
      AFN[mt] = *(const short8*)(Lr_ + baseA + (rmtg) * 4096 + mt * 1024);   \
    if (RB) {                                                                \
      _Pragma("unroll")                                                      \
      for (int nt = 0; nt < 4; ++nt)                                         \
        BFN[nt] = *(const short8*)(Lr_ + baseB + nt * 1024);                 \
    }                                                                        \
    STG(sb, smat, skh, skt);                                                 \
    __builtin_amdgcn_sched_barrier(0);                                       \
    if (VMW) asm volatile("s_waitcnt vmcnt(6)" ::: "memory");                \
    asm volatile("s_waitcnt lgkmcnt(" LGS ")" ::: "memory");                 \
    __builtin_amdgcn_sched_barrier(0);                                       \
    __builtin_amdgcn_s_setprio(1);                                           \
    _Pragma("unroll")                                                        \
    for (int mt = 0; mt < 4; ++mt)                                           \
      _Pragma("unroll")                                                      \
      for (int nt = 0; nt < 4; ++nt)                                         \
        acc[(cmtg) * 4 + mt][nt] = __builtin_amdgcn_mfma_f32_16x16x32_bf16(  \
            AFC[mt], BFC[nt], acc[(cmtg) * 4 + mt][nt], 0, 0, 0);            \
    __builtin_amdgcn_s_setprio(0);                                           \
    __builtin_amdgcn_s_barrier();                                            \
    __builtin_amdgcn_sched_barrier(0);                                       \
  } while (0)

#pragma clang loop unroll(disable)
  for (int t2 = 0; t2 < KT1 / 2; ++t2) {
    const int n = 2 * t2;
    PH(0, 0, 0, afA, bfA,  0, 0, 1, afB, bfB, 0,  1, 0, 1, n + 1, 1, "4");
    PH(0, 0, 1, afB, bfA,  0, 1, 0, afA, bfB, 1,  1, 1, 1, n + 1, 0, "8");
    PH(0, 1, 0, afA, bfB,  0, 1, 1, afB, bfA, 0,  0, 0, 0, n + 2, 1, "4");
    PH(0, 1, 1, afB, bfB,  1, 0, 0, afA, bfA, 1,  0, 1, 0, n + 2, 0, "8");
    PH(1, 0, 0, afA, bfA,  1, 0, 1, afB, bfB, 0,  0, 0, 1, n + 2, 1, "4");
    PH(1, 0, 1, afB, bfA,  1, 1, 0, afA, bfB, 1,  0, 1, 1, n + 2, 0, "8");
    PH(1, 1, 0, afA, bfB,  1, 1, 1, afB, bfA, 0,  1, 0, 0, n + 3, 1, "4");
    PH(1, 1, 1, afB, bfB,  0, 0, 0, afA, bfA, 1,  1, 1, 0, n + 3, 0, "8");
  }
#undef PH
#undef STG

  // ======================= fused epilogue (v3) =========================
  // Drain all outstanding staging (tail prefetches) + frag reads, then the
  // staging LDS is dead and can be reused as the 256x256 bf16 h-tile.
  asm volatile("s_waitcnt vmcnt(0) lgkmcnt(0)" ::: "memory");
  __builtin_amdgcn_s_barrier();
  __builtin_amdgcn_sched_barrier(0);

  const int gcol0 = blockIdx.y * 256 + wn;
  float bv[4];
#pragma unroll
  for (int nt = 0; nt < 4; ++nt) bv[nt] = bias[gcol0 + nt * 16 + r15];
  const size_t grow0 = (size_t)blockIdx.x * 256 + wm;

  // htile byte addr: row*512 + swizzled 16B slot + in-slot offset
#define HB(row, col) ((row) * 512 + (((((col) >> 3) ^ ((row) & 7))) << 4) + \
                      (((col) & 7) << 1))
#pragma unroll
  for (int mt = 0; mt < 8; ++mt) {
#pragma unroll
    for (int i = 0; i < 4; ++i) {
      const int lrow = wm + mt * 16 + quad * 4 + i;
      const size_t rb = (grow0 + mt * 16 + quad * 4 + i) * (size_t)N1;
#pragma unroll
      for (int nt = 0; nt < 4; ++nt) {
        const int lcol = wn + nt * 16 + r15;
        float v = fast_tanh(acc[mt][nt][i] + bv[nt]);
        hf32[rb + gcol0 - wn + lcol] = v;   // = rb + blockIdx.y*256 + lcol
        *(bf16*)(ldsb + HB(lrow, lcol)) = __float2bfloat16(v);
      }
    }
  }

  // mini-GEMM: out2[256r x 256n2] += htile[256r x 256k] @ W2slice^T
  // wave owns 128r x 64n2; k = 256 (8 slices of 32). B double-buffered in
  // regs; first two quads issued BEFORE the barrier (global loads, no LDS
  // dep) so the first L2 latency hides under the htile write + barrier.
  const bf16* w2base = W2b + (size_t)blockIdx.y * 256;  // k-slice of W2b[n2][2048]

#define MG_LOADB(BQ, ksn) do {                                               \
    _Pragma("unroll")                                                        \
    for (int nt = 0; nt < 4; ++nt)                                           \
      BQ[nt] = *(const short8*)(w2base +                                     \
                (size_t)(wn + nt * 16 + r15) * 2048 + (ksn) * 32 + quad * 8);\
  } while (0)
#define MG_STEP(BQ, ksc) do {                                                \
    short8 aq_[8];                                                           \
    _Pragma("unroll")                                                        \
    for (int mt = 0; mt < 8; ++mt) {                                         \
      const int row_ = wm + mt * 16 + r15;                                   \
      aq_[mt] = *(const short8*)(ldsb + row_ * 512 +                         \
                                 ((((ksc) * 4 + quad) ^ (row_ & 7))) * 16);  \
    }                                                                        \
    _Pragma("unroll")                                                        \
    for (int mt = 0; mt < 8; ++mt)                                           \
      _Pragma("unroll")                                                      \
      for (int nt = 0; nt < 4; ++nt)                                         \
        acc[mt][nt] = __builtin_amdgcn_mfma_f32_16x16x32_bf16(               \
            aq_[mt], BQ[nt], acc[mt][nt], 0, 0, 0);                          \
  } while (0)

  short8 bqA[4], bqB[4];
  MG_LOADB(bqA, 0);
  MG_LOADB(bqB, 1);
  asm volatile("s_waitcnt lgkmcnt(0)" ::: "memory");
  __builtin_amdgcn_s_barrier();
  __builtin_amdgcn_sched_barrier(0);

#pragma unroll
  for (int i = 0; i < 8; i++)
#pragma unroll
    for (int j = 0; j < 4; j++) acc[i][j] = z;

  MG_LOADB(bqA, 2); MG_STEP(bqB, 1);   // note: bqA/bqB roles below keep
  // the ks order: consume 0 first. Re-order: consume bqA(0) before loading
  // into it. Corrected sequence:
#undef MG_LOADB
#define MG_LOADB(BQ, ksn) do {                                               \
    _Pragma("unroll")                                                        \
    for (int nt = 0; nt < 4; ++nt)                                           \
      BQ[nt] = *(const short8*)(w2base +                                     \
                (size_t)(wn + nt * 16 + r15) * 2048 + (ksn) * 32 + quad * 8);\
  } while (0)
  // (sequence fixed below; the stray MG_STEP above consumed bqB(1) early —
  //  undo by recomputing: actually restart cleanly)
#pragma unroll
  for (int i = 0; i < 8; i++)
#pragma unroll
    for (int j = 0; j < 4; j++) acc[i][j] = z;
  MG_LOADB(bqA, 0); MG_LOADB(bqB, 1);
  MG_LOADB_DUMMY:;
  {
    short8 bqC[4];
    MG_LOADB(bqC, 2); MG_STEP(bqA, 0);
    MG_LOADB(bqA, 3); MG_STEP(bqB, 1);
    MG_LOADB(bqB, 4); MG_STEP(bqC, 2);
    MG_LOADB(bqC, 5); MG_STEP(bqA, 3);
    MG_LOADB(bqA, 6); MG_STEP(bqB, 4);
    MG_LOADB(bqB, 7); MG_STEP(bqC, 5);
    MG_STEP(bqA, 6);
    MG_STEP(bqB, 7);
  }
#undef MG_LOADB
#undef MG_STEP
#undef HB

  // emit partial (MODE 1: bf16 stores to part[by]; MODE 0: atomics to out)
  const size_t slab = (size_t)blockIdx.y * BATCH * N2;
#pragma unroll
  for (int mt = 0; mt < 8; ++mt) {
#pragma unroll
    for (int i = 0; i < 4; ++i) {
      const size_t gr = grow0 + mt * 16 + quad * 4 + i;
#pragma unroll
      for (int nt = 0; nt < 4; ++nt) {
        const int gc = wn + nt * 16 + r15;
        if (MODE == 0) {
          unsafeAtomicAdd(&outp[gr * N2 + gc], acc[mt][nt][i]);
        } else {
          partp[slab + gr * N2 + gc] = __float2bfloat16(acc[mt][nt][i]);
        }
      }
    }
  }
}

extern "C" void kernel_launch(void* const* d_in, const int* in_sizes, int n_in,
                              void* d_out, int out_size, void* d_ws,
                              size_t ws_size, hipStream_t stream) {
  const float* x     = (const float*)d_in[0];  // [8192, 256]
  const float* h     = (const float*)d_in[1];  // [8192, 2048]
  const float* W_i2h = (const float*)d_in[2];  // [2048, 2304]
  const float* b_i2h = (const float*)d_in[3];  // [2048]
  const float* W_h2o = (const float*)d_in[4];  // [256, 2048]
  const float* b_h2o = (const float*)d_in[5];  // [256]

  float* out       = (float*)d_out;                    // [8192, 256]
  float* hnew_f32  = out + (size_t)BATCH * N2;         // [8192, 2048]

  bf16* comb   = (bf16*)d_ws;                          // 8192*2304  (37.75 MB)
  bf16* Wi2h_b = comb + (size_t)BATCH * K1;            // 2048*2304  ( 9.44 MB)
  bf16* Wh2o_b = Wi2h_b + (size_t)N1 * K1;             // 256*2048   ( 1.00 MB)
  bf16* part   = Wh2o_b + (size_t)N2 * K2;             // 8*8192*256 (33.55 MB)

  const size_t ws_needed = (size_t)BATCH * K1 * 2 + (size_t)N1 * K1 * 2 +
                           (size_t)N2 * K2 * 2 + (size_t)8 * BATCH * N2 * 2;
  const bool big_ws = ws_size >= ws_needed;

  // fused converters (+ bias seed only for the atomic fallback path)
  prep<<<(SEG0 + SEG1 + SEG2 + SEG3) / 256, 256, 0, stream>>>(
      x, h, W_i2h, W_h2o, b_h2o, comb, Wi2h_b, Wh2o_b,
      big_ws ? nullptr : out);

  if (big_ws) {
    gemm1_tanh<1><<<dim3(BATCH / 256, N1 / 256), 512, 0, stream>>>(
        comb, Wi2h_b, b_i2h, Wh2o_b, hnew_f32, nullptr, part);
    reduce8<<<(BATCH * N2 / 8) / 256, 256, 0, stream>>>(part, b_h2o, out);
  } else {
    gemm1_tanh<0><<<dim3(BATCH / 256, N1 / 256), 512, 0, stream>>>(
        comb, Wi2h_b, b_i2h, Wh2o_b, hnew_f32, out, nullptr);
  }
}